// Round 4
// baseline (872.043 us; speedup 1.0000x reference)
//
#include <hip/hip_runtime.h>

typedef __attribute__((ext_vector_type(8))) short short8;
typedef __attribute__((ext_vector_type(4))) short bf16x4;
typedef __attribute__((ext_vector_type(4))) float f32x4;

__device__ __forceinline__ f32x4 mfma16(short8 a, short8 b, f32x4 c) {
  return __builtin_amdgcn_mfma_f32_16x16x32_bf16(a, b, c, 0, 0, 0);
}

__device__ __forceinline__ short f2bf(float f) {  // RNE float->bf16
  union { float f; unsigned u; } v; v.f = f;
  unsigned r = (v.u + 0x7fffu + ((v.u >> 16) & 1u)) >> 16;
  return (short)r;
}

// Async global->LDS, 16B per lane. LDS dest must be the wave-uniform base;
// HW writes base + lane*16 (linear). Source address is per-lane.
__device__ __forceinline__ void gload16(const short* g, short* l) {
  __builtin_amdgcn_global_load_lds(
      (const __attribute__((address_space(1))) void*)g,
      (__attribute__((address_space(3))) void*)l, 16, 0, 0);
}

// ---------------- fp32 -> bf16 streaming convert ----------------
__global__ __launch_bounds__(256) void cvt_k(const float* __restrict__ src,
                                             short* __restrict__ dst, long n8) {
  long i = (long)blockIdx.x * 256 + threadIdx.x;
  const long stride = (long)gridDim.x * 256;
  for (; i < n8; i += stride) {
    float4 a = *(const float4*)(src + i * 8);
    float4 b = *(const float4*)(src + i * 8 + 4);
    short8 o = {f2bf(a.x), f2bf(a.y), f2bf(a.z), f2bf(a.w),
                f2bf(b.x), f2bf(b.y), f2bf(b.z), f2bf(b.w)};
    *(short8*)(dst + i * 8) = o;
  }
}

// =============== 256x256 8-phase GEMM core (K=768, BK=64) ===============
// 512 threads = 8 waves (wm = wv&1 row-half, wn = wv>>1 col-quarter).
// LDS 128 KiB: buf b (=ktile&1): A half h at b*65536 + h*16384;
//              B half h at b*65536 + 32768 + h*16384.
// Half layout: [colblk(2)][row(128)][32 bf16], swizzle byte ^= ((byte>>9)&1)<<5
// (st_16x32). global_load_lds writes linearly -> inverse-swizzled SOURCE.
// Phases (balanced reads 8/8/4/4, one ks per 16-MFMA phase; B frags
// register-reused across the m4-7 phases):
//   P0: rd A m0-3 ks0 + B ks0; stage A-top(t+1)
//   P1: rd A m0-3 ks1 + B ks1; stage A-bot(t+1)
//   P2: rd A m4-7 ks0;         stage B-top(t+2)
//   P3: rd A m4-7 ks1;         stage B-bot(t+2); vmcnt(4)
// vmcnt(4) once per K-tile: leaves the 4 B(t+2) loads in flight, guarantees
// tile t+1 fully landed (A(t+1) staged this tile, B(t+1) staged last tile).
__device__ __forceinline__ void gemm256_core(
    const short* a00, const short* a01, const short* a10, const short* a11,
    const short* b00, const short* b01, const short* b10, const short* b11,
    char* lds, int wv, int lane, f32x4 (&acc)[8][4]) {
  const int l15 = lane & 15, q4 = lane >> 4;
  const int wm = wv & 1, wn = wv >> 1;
  const char* rdA = lds + wm * 16384;
  const char* rdB = lds + 32768 + (wn >> 1) * 16384;
  const int rB0 = (wn & 1) * 64;

  auto stg = [&](int T, int h, int tt) {
    const int t = tt >= 12 ? tt - 12 : tt;  // wrap: harmless, in-bounds
    char* d = lds + (t & 1) * 65536 + T * 32768 + h * 16384 + wv * 2048;
    const short* g0 = T ? (h ? b10 : b00) : (h ? a10 : a00);
    const short* g1 = T ? (h ? b11 : b01) : (h ? a11 : a01);
    gload16(g0 + t * 64, (short*)d);
    gload16(g1 + t * 64, (short*)(d + 1024));
  };
  auto rdfrag = [&](const char* base, int rowl, int ks) -> short8 {
    int off = ks * 8192 + rowl * 64 + q4 * 16;
    off ^= ((off >> 9) & 1) << 5;
    return *(const short8*)(base + off);
  };

  // prologue: K0 fully + B halves of K1; wait K0 landed
  stg(0, 0, 0); stg(0, 1, 0); stg(1, 0, 0); stg(1, 1, 0);
  stg(1, 0, 1); stg(1, 1, 1);
  asm volatile("s_waitcnt vmcnt(4)" ::: "memory");
  __builtin_amdgcn_s_barrier();

  auto ktile = [&](int buf, int t) {
    const char* A = rdA + buf * 65536;
    const char* B = rdB + buf * 65536;
    short8 afl[4], bfr[4][2];
    // ---- P0 ----
#pragma unroll
    for (int m = 0; m < 4; ++m) afl[m] = rdfrag(A, m * 16 + l15, 0);
#pragma unroll
    for (int n = 0; n < 4; ++n) bfr[n][0] = rdfrag(B, rB0 + n * 16 + l15, 0);
    stg(0, 0, t + 1);
    __builtin_amdgcn_s_barrier();
    __builtin_amdgcn_s_setprio(1);
#pragma unroll
    for (int m = 0; m < 4; ++m)
#pragma unroll
      for (int n = 0; n < 4; ++n)
        acc[m][n] = mfma16(afl[m], bfr[n][0], acc[m][n]);
    __builtin_amdgcn_s_setprio(0);
    __builtin_amdgcn_s_barrier();
    // ---- P1 ----
#pragma unroll
    for (int m = 0; m < 4; ++m) afl[m] = rdfrag(A, m * 16 + l15, 1);
#pragma unroll
    for (int n = 0; n < 4; ++n) bfr[n][1] = rdfrag(B, rB0 + n * 16 + l15, 1);
    stg(0, 1, t + 1);
    __builtin_amdgcn_s_barrier();
    __builtin_amdgcn_s_setprio(1);
#pragma unroll
    for (int m = 0; m < 4; ++m)
#pragma unroll
      for (int n = 0; n < 4; ++n)
        acc[m][n] = mfma16(afl[m], bfr[n][1], acc[m][n]);
    __builtin_amdgcn_s_setprio(0);
    __builtin_amdgcn_s_barrier();
    // ---- P2 ----
#pragma unroll
    for (int m = 0; m < 4; ++m) afl[m] = rdfrag(A, (m + 4) * 16 + l15, 0);
    stg(1, 0, t + 2);
    __builtin_amdgcn_s_barrier();
    __builtin_amdgcn_s_setprio(1);
#pragma unroll
    for (int m = 0; m < 4; ++m)
#pragma unroll
      for (int n = 0; n < 4; ++n)
        acc[m + 4][n] = mfma16(afl[m], bfr[n][0], acc[m + 4][n]);
    __builtin_amdgcn_s_setprio(0);
    __builtin_amdgcn_s_barrier();
    // ---- P3 ----
#pragma unroll
    for (int m = 0; m < 4; ++m) afl[m] = rdfrag(A, (m + 4) * 16 + l15, 1);
    stg(1, 1, t + 2);
    __builtin_amdgcn_s_barrier();
    __builtin_amdgcn_s_setprio(1);
#pragma unroll
    for (int m = 0; m < 4; ++m)
#pragma unroll
      for (int n = 0; n < 4; ++n)
        acc[m + 4][n] = mfma16(afl[m], bfr[n][1], acc[m + 4][n]);
    __builtin_amdgcn_s_setprio(0);
    asm volatile("s_waitcnt vmcnt(4)" ::: "memory");
    __builtin_amdgcn_s_barrier();
  };

  for (int g = 0; g < 6; ++g) {
    ktile(0, 2 * g);
    ktile(1, 2 * g + 1);
  }
}

// per-thread staging geometry: slot s = wv*128 + j*64 + lane covers LDS
// phys bytes [s*16, s*16+16); unswizzled u = s*16 ^ (((s>>5)&1)<<5):
// colblk = s>>9, row = (s>>2)&127, colbyte = ((s&3)<<4) ^ (((s>>5)&1)<<5).
__device__ __forceinline__ void stage_geom(int wv, int lane, int* srow, int* coff) {
#pragma unroll
  for (int j = 0; j < 2; ++j) {
    const int s = wv * 128 + j * 64 + lane;
    srow[j] = (s >> 2) & 127;
    coff[j] = (s >> 9) * 32 + (((((s & 3) << 4) ^ (((s >> 5) & 1) << 5))) >> 1);
  }
}

// ---------------- QKV GEMM: O[r][j] = sum_k X[r][k] * W[j][k] ----------------
__global__ __launch_bounds__(512, 2) void gemm_qkv_k(
    const short* __restrict__ A0, const short* __restrict__ A1,
    const short* __restrict__ W,
    short* __restrict__ O0, short* __restrict__ O1) {
  extern __shared__ char lds[];
  const int tid = threadIdx.x, lane = tid & 63, wv = tid >> 6;
  const int l15 = lane & 15, q4 = lane >> 4;
  const int m0 = blockIdx.x * 256, n0 = blockIdx.y * 256;
  const short* A = blockIdx.z ? A1 : A0;
  short* O = blockIdx.z ? O1 : O0;

  int srow[2], coff[2];
  stage_geom(wv, lane, srow, coff);
  const short* a00 = A + (long)(m0 + srow[0]) * 768 + coff[0];
  const short* a01 = A + (long)(m0 + srow[1]) * 768 + coff[1];
  const short* a10 = A + (long)(m0 + 128 + srow[0]) * 768 + coff[0];
  const short* a11 = A + (long)(m0 + 128 + srow[1]) * 768 + coff[1];
  const short* b00 = W + (long)(n0 + srow[0]) * 768 + coff[0];
  const short* b01 = W + (long)(n0 + srow[1]) * 768 + coff[1];
  const short* b10 = W + (long)(n0 + 128 + srow[0]) * 768 + coff[0];
  const short* b11 = W + (long)(n0 + 128 + srow[1]) * 768 + coff[1];

  f32x4 acc[8][4] = {};
  gemm256_core(a00, a01, a10, a11, b00, b01, b10, b11, lds, wv, lane, acc);

  const int wm = wv & 1, wn = wv >> 1;
#pragma unroll
  for (int m = 0; m < 8; ++m)
#pragma unroll
    for (int n = 0; n < 4; ++n) {
      const int col = n0 + wn * 64 + n * 16 + l15;
#pragma unroll
      for (int r = 0; r < 4; ++r) {
        const int row = m0 + wm * 128 + m * 16 + q4 * 4 + r;
        O[(long)row * 2304 + col] = f2bf(acc[m][n][r]);
      }
    }
}

// ---------------- Flash attention (ws bf16 in, ws bf16 out) ----------------
// One block = ALL queries of one (b,h,kind): 4 waves x QW q-rows each.
// Online softmax over KT 64-key K/V tiles (double-buffered, 1 barrier/tile).
// Each kf/vf LDS fragment read feeds MB MFMAs (vs 1 in the old per-64q kernel).
// NK=128: mt (kind ignored, q rows 0..127). NK=384: s (kind 0) / s_hsi (kind 1),
// q rows 128..383.
template <int NK, int QW>
__global__ __launch_bounds__(256, 2) void attn_f(
    const short* __restrict__ qkvx, const short* __restrict__ qkvh,
    short* __restrict__ omt, short* __restrict__ os, short* __restrict__ osh) {
  constexpr int KT = NK / 64;
  constexpr int MB = QW / 16;
  __shared__ __align__(16) short kk[2][64 * 72];   // K tiles
  __shared__ __align__(16) short vvs[2][64 * 72];  // swizzled V^T tiles
  __shared__ __align__(16) short sp[4][QW * 72];   // per-wave P tile (swizzled)

  const int tid = threadIdx.x, lane = tid & 63, wv = tid >> 6;
  const int l15 = lane & 15, q4 = lane >> 4;
  const int b = blockIdx.x, h = blockIdx.y, kind = blockIdx.z;

  const short* src = kind ? qkvh : qkvx;
  short* outb;
  int q0;
  if (NK == 128) {
    outb = omt + ((long)b * 128) * 768 + h * 64;
    q0 = 0;
  } else {
    outb = (kind ? osh : os) + ((long)b * 256) * 768 + h * 64;
    q0 = 128;
  }
  const short* qb = src + ((long)(b * 384 + q0 + wv * QW)) * 2304 + h * 64;
  const short* kb = src + (long)b * 384 * 2304 + 768 + h * 64;
  const short* vb = kb + 768;

  // staging slots: thread covers (key0,dg0) and (key0+32,dg0)
  const int key0 = tid >> 3, dg0 = tid & 7;
  const int key1 = key0 + 32;

  // Q fragments (persistent)
  short8 qf[MB][2];
#pragma unroll
  for (int m = 0; m < MB; ++m)
#pragma unroll
    for (int ks = 0; ks < 2; ++ks)
      qf[m][ks] = *(const short8*)(qb + (long)(m * 16 + l15) * 2304 + ks * 32 + q4 * 8);

  float mxr[MB][4], smr[MB][4];
  f32x4 oacc[MB][4] = {};
#pragma unroll
  for (int m = 0; m < MB; ++m)
#pragma unroll
    for (int r = 0; r < 4; ++r) { mxr[m][r] = -3e30f; smr[m][r] = 0.f; }

  short8 ka0 = *(const short8*)(kb + (long)key0 * 2304 + dg0 * 8);
  short8 ka1 = *(const short8*)(kb + (long)key1 * 2304 + dg0 * 8);
  short8 va0 = *(const short8*)(vb + (long)key0 * 2304 + dg0 * 8);
  short8 va1 = *(const short8*)(vb + (long)key1 * 2304 + dg0 * 8);

  const float scale = 0.125f;
  char* spw = (char*)&sp[wv][0];

  for (int kt = 0; kt < KT; ++kt) {
    const int buf = kt & 1;
    // K tile (vector writes) + V^T tile (scalar transpose, XOR-swizzled)
    *(short8*)&kk[buf][key0 * 72 + dg0 * 8] = ka0;
    *(short8*)&kk[buf][key1 * 72 + dg0 * 8] = ka1;
    char* vt = (char*)&vvs[buf][0];
#pragma unroll
    for (int e = 0; e < 8; ++e) {
      const int d0 = dg0 * 8 + e;
      *(short*)(vt + ((d0 * 144 + key0 * 2) ^ (dg0 << 4))) = va0[e];
      *(short*)(vt + ((d0 * 144 + key1 * 2) ^ (dg0 << 4))) = va1[e];
    }
    __syncthreads();
    if (kt + 1 < KT) {
      ka0 = *(const short8*)(kb + (long)((kt + 1) * 64 + key0) * 2304 + dg0 * 8);
      ka1 = *(const short8*)(kb + (long)((kt + 1) * 64 + key1) * 2304 + dg0 * 8);
      va0 = *(const short8*)(vb + (long)((kt + 1) * 64 + key0) * 2304 + dg0 * 8);
      va1 = *(const short8*)(vb + (long)((kt + 1) * 64 + key1) * 2304 + dg0 * 8);
    }

    // ---- S = Q K^T for this tile ----
    f32x4 sacc[MB][4] = {};
#pragma unroll
    for (int n = 0; n < 4; ++n) {
      short8 kf0 = *(const short8*)&kk[buf][(n * 16 + l15) * 72 + q4 * 8];
      short8 kf1 = *(const short8*)&kk[buf][(n * 16 + l15) * 72 + 32 + q4 * 8];
#pragma unroll
      for (int m = 0; m < MB; ++m) {
        sacc[m][n] = mfma16(qf[m][0], kf0, sacc[m][n]);
        sacc[m][n] = mfma16(qf[m][1], kf1, sacc[m][n]);
      }
    }

    // ---- online softmax update + P write (bf16, swizzled) ----
#pragma unroll
    for (int m = 0; m < MB; ++m) {
      float pm[4];
#pragma unroll
      for (int r = 0; r < 4; ++r)
        pm[r] = fmaxf(fmaxf(sacc[m][0][r], sacc[m][1][r]),
                      fmaxf(sacc[m][2][r], sacc[m][3][r]));
#pragma unroll
      for (int r = 0; r < 4; ++r) {
        pm[r] = fmaxf(pm[r], __shfl_xor(pm[r], 1));
        pm[r] = fmaxf(pm[r], __shfl_xor(pm[r], 2));
        pm[r] = fmaxf(pm[r], __shfl_xor(pm[r], 4));
        pm[r] = fmaxf(pm[r], __shfl_xor(pm[r], 8));
      }
#pragma unroll
      for (int r = 0; r < 4; ++r) {
        const float mnew = fmaxf(mxr[m][r], pm[r]);
        const float resc = __expf((mxr[m][r] - mnew) * scale);
        mxr[m][r] = mnew;
        smr[m][r] *= resc;
#pragma unroll
        for (int n2 = 0; n2 < 4; ++n2) oacc[m][n2][r] *= resc;
      }
#pragma unroll
      for (int n = 0; n < 4; ++n)
#pragma unroll
        for (int r = 0; r < 4; ++r) {
          const float e = __expf((sacc[m][n][r] - mxr[m][r]) * scale);
          smr[m][r] += e;
          const int row = m * 16 + q4 * 4 + r;
          const int byte = (row * 144 + (n * 16 + l15) * 2) ^ (((row >> 3) & 1) << 5);
          *(short*)(spw + byte) = f2bf(e);
        }
    }

    // ---- O += P V ----
#pragma unroll
    for (int ks = 0; ks < 2; ++ks) {
      short8 pf[MB];
#pragma unroll
      for (int m = 0; m < MB; ++m) {
        const int row = m * 16 + l15;
        const int byte = (row * 144 + ks * 64 + q4 * 16) ^ (((row >> 3) & 1) << 5);
        pf[m] = *(const short8*)(spw + byte);
      }
#pragma unroll
      for (int n2 = 0; n2 < 4; ++n2) {
        const int db = n2 * 16 + l15;
        short8 vf = *(const short8*)(vt + ((db * 144 + (ks * 32 + q4 * 8) * 2) ^
                                           (((db >> 3) & 7) << 4)));
#pragma unroll
        for (int m = 0; m < MB; ++m)
          oacc[m][n2] = mfma16(pf[m], vf, oacc[m][n2]);
      }
    }
  }

  // ---- epilogue: reduce row-sums, normalize, store ----
  short* ob = outb + (long)wv * QW * 768;
#pragma unroll
  for (int m = 0; m < MB; ++m)
#pragma unroll
    for (int r = 0; r < 4; ++r) {
      float s = smr[m][r];
      s += __shfl_xor(s, 1);
      s += __shfl_xor(s, 2);
      s += __shfl_xor(s, 4);
      s += __shfl_xor(s, 8);
      const float inv = 1.f / s;
#pragma unroll
      for (int n2 = 0; n2 < 4; ++n2)
        ob[(m * 16 + q4 * 4 + r) * 768 + n2 * 16 + l15] = f2bf(oacc[m][n2][r] * inv);
    }
}

// ------- Proj GEMM: out[r][j] = sum_k Xa[r][k]*Pw[j][k] + pb[j] (fp32 out) -----
__global__ __launch_bounds__(512, 2) void gemm_proj_k(
    const short* __restrict__ mt, const short* __restrict__ sA,
    const short* __restrict__ sh,
    const short* __restrict__ W, const float* __restrict__ bias,
    float* __restrict__ out, int cb0) {
  extern __shared__ char lds[];
  const int tid = threadIdx.x, lane = tid & 63, wv = tid >> 6;
  const int l15 = lane & 15, q4 = lane >> 4;
  const int m0 = blockIdx.x * 256, n0 = blockIdx.y * 256;
  const short* s = blockIdx.z ? sh : sA;

  int srow[2], coff[2];
  stage_geom(wv, lane, srow, coff);
  auto arow = [&](int r) -> const short* {
    const int ba = r / 384, na = r % 384;
    return na < 128 ? (mt + ((long)ba * 128 + na) * 768)
                    : (s + ((long)ba * 256 + (na - 128)) * 768);
  };
  const short* a00 = arow(m0 + srow[0]) + coff[0];
  const short* a01 = arow(m0 + srow[1]) + coff[1];
  const short* a10 = arow(m0 + 128 + srow[0]) + coff[0];
  const short* a11 = arow(m0 + 128 + srow[1]) + coff[1];
  const short* b00 = W + (long)(n0 + srow[0]) * 768 + coff[0];
  const short* b01 = W + (long)(n0 + srow[1]) * 768 + coff[1];
  const short* b10 = W + (long)(n0 + 128 + srow[0]) * 768 + coff[0];
  const short* b11 = W + (long)(n0 + 128 + srow[1]) * 768 + coff[1];

  f32x4 acc[8][4] = {};
  gemm256_core(a00, a01, a10, a11, b00, b01, b10, b11, lds, wv, lane, acc);

  const int wm = wv & 1, wn = wv >> 1;
#pragma unroll
  for (int n = 0; n < 4; ++n) {
    const int col = n0 + wn * 64 + n * 16 + l15;
    const float bvv = bias[col];
#pragma unroll
    for (int m = 0; m < 8; ++m)
#pragma unroll
      for (int r = 0; r < 4; ++r) {
        const int row = m0 + wm * 128 + m * 16 + q4 * 4 + r;
        out[(long)blockIdx.z * 18874368 + ((long)cb0 * 384 + row) * 768 + col] =
            acc[m][n][r] + bvv;
      }
  }
}

extern "C" void kernel_launch(void* const* d_in, const int* in_sizes, int n_in,
                              void* d_out, int out_size, void* d_ws, size_t ws_size,
                              hipStream_t stream) {
  (void)in_sizes; (void)n_in; (void)out_size;
  const float* x  = (const float*)d_in[0];
  const float* xh = (const float*)d_in[1];
  const float* qw = (const float*)d_in[2];
  const float* pw = (const float*)d_in[3];
  const float* pb = (const float*)d_in[4];
  float* out = (float*)d_out;

  const long qwSz = 2304L * 768 * 2;
  const long pwSz = 768L * 768 * 2;
  const long fixedW = qwSz + pwSz;
  const long perBatch = (2L * 384 * 768 + 2L * 384 * 2304 + 640L * 768) * 2;
  int CB = 64;
  while (CB > 2 && (long)CB * perBatch + fixedW > (long)ws_size) CB >>= 1;

  char* ws = (char*)d_ws;
  short* qwbf = (short*)ws;
  short* pwbf = (short*)(ws + qwSz);
  char* dyn = ws + fixedW;
  const long xbfSz = (long)CB * 384 * 768 * 2;
  const long qkvSz = (long)CB * 384 * 2304 * 2;
  const long mtSz  = (long)CB * 128 * 768 * 2;
  const long sSz   = (long)CB * 256 * 768 * 2;
  short* xbf  = (short*)dyn;
  short* xhbf = (short*)(dyn + xbfSz);
  short* qkvx = (short*)(dyn + 2 * xbfSz);
  short* qkvh = (short*)(dyn + 2 * xbfSz + qkvSz);
  short* amt  = (short*)(dyn + 2 * xbfSz + 2 * qkvSz);
  short* as_  = (short*)(dyn + 2 * xbfSz + 2 * qkvSz + mtSz);
  short* ash  = (short*)(dyn + 2 * xbfSz + 2 * qkvSz + mtSz + sSz);

  cvt_k<<<864, 256, 0, stream>>>(qw, qwbf, 2304L * 768 / 8);
  cvt_k<<<288, 256, 0, stream>>>(pw, pwbf, 768L * 768 / 8);

  const int nch = 64 / CB;
  for (int c = 0; c < nch; ++c) {
    const int cb0 = c * CB;
    const long n8 = (long)CB * 384 * 768 / 8;
    cvt_k<<<2048, 256, 0, stream>>>(x + (long)cb0 * 384 * 768, xbf, n8);
    cvt_k<<<2048, 256, 0, stream>>>(xh + (long)cb0 * 384 * 768, xhbf, n8);
    dim3 g1((CB * 384) / 256, 9, 2);
    gemm_qkv_k<<<g1, 512, 131072, stream>>>(xbf, xhbf, qwbf, qkvx, qkvh);
    attn_f<128, 32><<<dim3(CB, 12, 1), 256, 0, stream>>>(qkvx, qkvh, amt, as_, ash);
    attn_f<384, 64><<<dim3(CB, 12, 2), 256, 0, stream>>>(qkvx, qkvh, amt, as_, ash);
    dim3 g3((CB * 384) / 256, 3, 2);
    gemm_proj_k<<<g3, 512, 131072, stream>>>(amt, as_, ash, pwbf, pb, out, cb0);
  }
}

// Round 5
// 666.280 us; speedup vs baseline: 1.3088x; 1.3088x over previous
//
#include <hip/hip_runtime.h>

typedef __attribute__((ext_vector_type(8))) short short8;
typedef __attribute__((ext_vector_type(4))) short bf16x4;
typedef __attribute__((ext_vector_type(4))) float f32x4;

__device__ __forceinline__ f32x4 mfma16(short8 a, short8 b, f32x4 c) {
  return __builtin_amdgcn_mfma_f32_16x16x32_bf16(a, b, c, 0, 0, 0);
}

__device__ __forceinline__ short f2bf(float f) {  // RNE float->bf16
  union { float f; unsigned u; } v; v.f = f;
  unsigned r = (v.u + 0x7fffu + ((v.u >> 16) & 1u)) >> 16;
  return (short)r;
}

// Async global->LDS, 16B per lane. LDS dest must be the wave-uniform base;
// HW writes base + lane*16 (linear). Source address is per-lane.
__device__ __forceinline__ void gload16(const short* g, short* l) {
  __builtin_amdgcn_global_load_lds(
      (const __attribute__((address_space(1))) void*)g,
      (__attribute__((address_space(3))) void*)l, 16, 0, 0);
}

// ---------------- fp32 -> bf16 streaming convert ----------------
__global__ __launch_bounds__(256) void cvt_k(const float* __restrict__ src,
                                             short* __restrict__ dst, long n8) {
  long i = (long)blockIdx.x * 256 + threadIdx.x;
  const long stride = (long)gridDim.x * 256;
  for (; i < n8; i += stride) {
    float4 a = *(const float4*)(src + i * 8);
    float4 b = *(const float4*)(src + i * 8 + 4);
    short8 o = {f2bf(a.x), f2bf(a.y), f2bf(a.z), f2bf(a.w),
                f2bf(b.x), f2bf(b.y), f2bf(b.z), f2bf(b.w)};
    *(short8*)(dst + i * 8) = o;
  }
}

// =============== 256x256 8-phase GEMM core (K=768, BK=64) ===============
// 512 threads = 8 waves (wm = wv&1 row-half, wn = wv>>1 col-quarter).
// LDS 128 KiB: buf b (=ktile&1): A half h at b*65536 + h*16384;
//              B half h at b*65536 + 32768 + h*16384.
// Half layout: [colblk(2)][row(128)][32 bf16], swizzle byte ^= ((byte>>9)&1)<<5
// (st_16x32). global_load_lds writes linearly -> inverse-swizzled SOURCE.
// Phases (balanced reads 8/8/4/4, one ks per 16-MFMA phase; B frags
// register-reused across the m4-7 phases):
//   P0: rd A m0-3 ks0 + B ks0; stage A-top(t+1)
//   P1: rd A m0-3 ks1 + B ks1; stage A-bot(t+1)
//   P2: rd A m4-7 ks0;         stage B-top(t+2)
//   P3: rd A m4-7 ks1;         stage B-bot(t+2); vmcnt(4)
__device__ __forceinline__ void gemm256_core(
    const short* a00, const short* a01, const short* a10, const short* a11,
    const short* b00, const short* b01, const short* b10, const short* b11,
    char* lds, int wv, int lane, f32x4 (&acc)[8][4]) {
  const int l15 = lane & 15, q4 = lane >> 4;
  const int wm = wv & 1, wn = wv >> 1;
  const char* rdA = lds + wm * 16384;
  const char* rdB = lds + 32768 + (wn >> 1) * 16384;
  const int rB0 = (wn & 1) * 64;

  auto stg = [&](int T, int h, int tt) {
    const int t = tt >= 12 ? tt - 12 : tt;  // wrap: harmless, in-bounds
    char* d = lds + (t & 1) * 65536 + T * 32768 + h * 16384 + wv * 2048;
    const short* g0 = T ? (h ? b10 : b00) : (h ? a10 : a00);
    const short* g1 = T ? (h ? b11 : b01) : (h ? a11 : a01);
    gload16(g0 + t * 64, (short*)d);
    gload16(g1 + t * 64, (short*)(d + 1024));
  };
  auto rdfrag = [&](const char* base, int rowl, int ks) -> short8 {
    int off = ks * 8192 + rowl * 64 + q4 * 16;
    off ^= ((off >> 9) & 1) << 5;
    return *(const short8*)(base + off);
  };

  // prologue: K0 fully + B halves of K1; wait K0 landed
  stg(0, 0, 0); stg(0, 1, 0); stg(1, 0, 0); stg(1, 1, 0);
  stg(1, 0, 1); stg(1, 1, 1);
  asm volatile("s_waitcnt vmcnt(4)" ::: "memory");
  __builtin_amdgcn_s_barrier();

  auto ktile = [&](int buf, int t) {
    const char* A = rdA + buf * 65536;
    const char* B = rdB + buf * 65536;
    short8 afl[4], bfr[4][2];
    // ---- P0 ----
#pragma unroll
    for (int m = 0; m < 4; ++m) afl[m] = rdfrag(A, m * 16 + l15, 0);
#pragma unroll
    for (int n = 0; n < 4; ++n) bfr[n][0] = rdfrag(B, rB0 + n * 16 + l15, 0);
    stg(0, 0, t + 1);
    __builtin_amdgcn_s_barrier();
    __builtin_amdgcn_s_setprio(1);
#pragma unroll
    for (int m = 0; m < 4; ++m)
#pragma unroll
      for (int n = 0; n < 4; ++n)
        acc[m][n] = mfma16(afl[m], bfr[n][0], acc[m][n]);
    __builtin_amdgcn_s_setprio(0);
    __builtin_amdgcn_s_barrier();
    // ---- P1 ----
#pragma unroll
    for (int m = 0; m < 4; ++m) afl[m] = rdfrag(A, m * 16 + l15, 1);
#pragma unroll
    for (int n = 0; n < 4; ++n) bfr[n][1] = rdfrag(B, rB0 + n * 16 + l15, 1);
    stg(0, 1, t + 1);
    __builtin_amdgcn_s_barrier();
    __builtin_amdgcn_s_setprio(1);
#pragma unroll
    for (int m = 0; m < 4; ++m)
#pragma unroll
      for (int n = 0; n < 4; ++n)
        acc[m][n] = mfma16(afl[m], bfr[n][1], acc[m][n]);
    __builtin_amdgcn_s_setprio(0);
    __builtin_amdgcn_s_barrier();
    // ---- P2 ----
#pragma unroll
    for (int m = 0; m < 4; ++m) afl[m] = rdfrag(A, (m + 4) * 16 + l15, 0);
    stg(1, 0, t + 2);
    __builtin_amdgcn_s_barrier();
    __builtin_amdgcn_s_setprio(1);
#pragma unroll
    for (int m = 0; m < 4; ++m)
#pragma unroll
      for (int n = 0; n < 4; ++n)
        acc[m + 4][n] = mfma16(afl[m], bfr[n][0], acc[m + 4][n]);
    __builtin_amdgcn_s_setprio(0);
    __builtin_amdgcn_s_barrier();
    // ---- P3 ----
#pragma unroll
    for (int m = 0; m < 4; ++m) afl[m] = rdfrag(A, (m + 4) * 16 + l15, 1);
    stg(1, 1, t + 2);
    __builtin_amdgcn_s_barrier();
    __builtin_amdgcn_s_setprio(1);
#pragma unroll
    for (int m = 0; m < 4; ++m)
#pragma unroll
      for (int n = 0; n < 4; ++n)
        acc[m + 4][n] = mfma16(afl[m], bfr[n][1], acc[m + 4][n]);
    __builtin_amdgcn_s_setprio(0);
    asm volatile("s_waitcnt vmcnt(4)" ::: "memory");
    __builtin_amdgcn_s_barrier();
  };

  for (int g = 0; g < 6; ++g) {
    ktile(0, 2 * g);
    ktile(1, 2 * g + 1);
  }
}

// per-thread staging geometry: slot s = wv*128 + j*64 + lane covers LDS
// phys bytes [s*16, s*16+16); unswizzled u = s*16 ^ (((s>>5)&1)<<5):
// colblk = s>>9, row = (s>>2)&127, colbyte = ((s&3)<<4) ^ (((s>>5)&1)<<5).
__device__ __forceinline__ void stage_geom(int wv, int lane, int* srow, int* coff) {
#pragma unroll
  for (int j = 0; j < 2; ++j) {
    const int s = wv * 128 + j * 64 + lane;
    srow[j] = (s >> 2) & 127;
    coff[j] = (s >> 9) * 32 + (((((s & 3) << 4) ^ (((s >> 5) & 1) << 5))) >> 1);
  }
}

// ---------------- QKV GEMM: O[r][j] = sum_k X[r][k] * W[j][k] ----------------
__global__ __launch_bounds__(512, 2) void gemm_qkv_k(
    const short* __restrict__ A0, const short* __restrict__ A1,
    const short* __restrict__ W,
    short* __restrict__ O0, short* __restrict__ O1) {
  extern __shared__ char lds[];
  const int tid = threadIdx.x, lane = tid & 63, wv = tid >> 6;
  const int l15 = lane & 15, q4 = lane >> 4;
  const int m0 = blockIdx.x * 256, n0 = blockIdx.y * 256;
  const short* A = blockIdx.z ? A1 : A0;
  short* O = blockIdx.z ? O1 : O0;

  int srow[2], coff[2];
  stage_geom(wv, lane, srow, coff);
  const short* a00 = A + (long)(m0 + srow[0]) * 768 + coff[0];
  const short* a01 = A + (long)(m0 + srow[1]) * 768 + coff[1];
  const short* a10 = A + (long)(m0 + 128 + srow[0]) * 768 + coff[0];
  const short* a11 = A + (long)(m0 + 128 + srow[1]) * 768 + coff[1];
  const short* b00 = W + (long)(n0 + srow[0]) * 768 + coff[0];
  const short* b01 = W + (long)(n0 + srow[1]) * 768 + coff[1];
  const short* b10 = W + (long)(n0 + 128 + srow[0]) * 768 + coff[0];
  const short* b11 = W + (long)(n0 + 128 + srow[1]) * 768 + coff[1];

  f32x4 acc[8][4] = {};
  gemm256_core(a00, a01, a10, a11, b00, b01, b10, b11, lds, wv, lane, acc);

  const int wm = wv & 1, wn = wv >> 1;
#pragma unroll
  for (int m = 0; m < 8; ++m)
#pragma unroll
    for (int n = 0; n < 4; ++n) {
      const int col = n0 + wn * 64 + n * 16 + l15;
#pragma unroll
      for (int r = 0; r < 4; ++r) {
        const int row = m0 + wm * 128 + m * 16 + q4 * 4 + r;
        O[(long)row * 2304 + col] = f2bf(acc[m][n][r]);
      }
    }
}

// ---------------- Flash attention (ws bf16 in, ws bf16 out) ----------------
// One block = ALL queries of one (b,h,kind): 8 waves x QW q-rows each
// (512 threads). Online softmax over KT 64-key K/V tiles (1 barrier/tile).
// MB = QW/16 kept small (<=2) so per-wave state fits registers (the round-4
// MB=4 version spilled ~80 VGPRs to scratch -> 356MB fetch, 324us).
// NK=128: mt (kind 0 only, q rows 0..127, QW=16). NK=384: s/s_hsi, q 128..383.
template <int NK, int QW>
__global__ __launch_bounds__(512, 2) void attn_f(
    const short* __restrict__ qkvx, const short* __restrict__ qkvh,
    short* __restrict__ omt, short* __restrict__ os, short* __restrict__ osh) {
  constexpr int KT = NK / 64;
  constexpr int MB = QW / 16;
  __shared__ __align__(16) short kk[2][64 * 72];   // K tiles
  __shared__ __align__(16) short vvs[2][64 * 72];  // swizzled V^T tiles
  __shared__ __align__(16) short sp[8][QW * 72];   // per-wave P tile (swizzled)

  const int tid = threadIdx.x, lane = tid & 63, wv = tid >> 6;
  const int l15 = lane & 15, q4 = lane >> 4;
  const int b = blockIdx.x, h = blockIdx.y, kind = blockIdx.z;

  const short* src = kind ? qkvh : qkvx;
  short* outb;
  int q0;
  if (NK == 128) {
    outb = omt + ((long)b * 128) * 768 + h * 64;
    q0 = 0;
  } else {
    outb = (kind ? osh : os) + ((long)b * 256) * 768 + h * 64;
    q0 = 128;
  }
  const short* qb = src + ((long)(b * 384 + q0 + wv * QW)) * 2304 + h * 64;
  const short* kb = src + (long)b * 384 * 2304 + 768 + h * 64;
  const short* vb = kb + 768;

  // staging: 512 slots = 64 keys x 8 dim-groups; one K + one V slot per thread
  const int key0 = tid >> 3, dg0 = tid & 7;

  // Q fragments (persistent)
  short8 qf[MB][2];
#pragma unroll
  for (int m = 0; m < MB; ++m)
#pragma unroll
    for (int ks = 0; ks < 2; ++ks)
      qf[m][ks] = *(const short8*)(qb + (long)(m * 16 + l15) * 2304 + ks * 32 + q4 * 8);

  float mxr[MB][4], smr[MB][4];
  f32x4 oacc[MB][4] = {};
#pragma unroll
  for (int m = 0; m < MB; ++m)
#pragma unroll
    for (int r = 0; r < 4; ++r) { mxr[m][r] = -3e30f; smr[m][r] = 0.f; }

  short8 ka = *(const short8*)(kb + (long)key0 * 2304 + dg0 * 8);
  short8 va = *(const short8*)(vb + (long)key0 * 2304 + dg0 * 8);

  const float scale = 0.125f;
  char* spw = (char*)&sp[wv][0];

  for (int kt = 0; kt < KT; ++kt) {
    const int buf = kt & 1;
    // K tile (vector write) + V^T tile (scalar transpose, XOR-swizzled:
    // bank = f(key, e^dg) covers all 32 banks, ~2 lanes/bank = free)
    *(short8*)&kk[buf][key0 * 72 + dg0 * 8] = ka;
    char* vt = (char*)&vvs[buf][0];
#pragma unroll
    for (int e = 0; e < 8; ++e) {
      const int d0 = dg0 * 8 + e;
      *(short*)(vt + ((d0 * 144 + key0 * 2) ^ (dg0 << 4))) = va[e];
    }
    __syncthreads();
    if (kt + 1 < KT) {
      ka = *(const short8*)(kb + (long)((kt + 1) * 64 + key0) * 2304 + dg0 * 8);
      va = *(const short8*)(vb + (long)((kt + 1) * 64 + key0) * 2304 + dg0 * 8);
    }

    // ---- S = Q K^T for this tile ----
    f32x4 sacc[MB][4] = {};
#pragma unroll
    for (int n = 0; n < 4; ++n) {
      short8 kf0 = *(const short8*)&kk[buf][(n * 16 + l15) * 72 + q4 * 8];
      short8 kf1 = *(const short8*)&kk[buf][(n * 16 + l15) * 72 + 32 + q4 * 8];
#pragma unroll
      for (int m = 0; m < MB; ++m) {
        sacc[m][n] = mfma16(qf[m][0], kf0, sacc[m][n]);
        sacc[m][n] = mfma16(qf[m][1], kf1, sacc[m][n]);
      }
    }

    // ---- online softmax update + P write (bf16, swizzled) ----
#pragma unroll
    for (int m = 0; m < MB; ++m) {
      float pm[4];
#pragma unroll
      for (int r = 0; r < 4; ++r)
        pm[r] = fmaxf(fmaxf(sacc[m][0][r], sacc[m][1][r]),
                      fmaxf(sacc[m][2][r], sacc[m][3][r]));
#pragma unroll
      for (int r = 0; r < 4; ++r) {
        pm[r] = fmaxf(pm[r], __shfl_xor(pm[r], 1));
        pm[r] = fmaxf(pm[r], __shfl_xor(pm[r], 2));
        pm[r] = fmaxf(pm[r], __shfl_xor(pm[r], 4));
        pm[r] = fmaxf(pm[r], __shfl_xor(pm[r], 8));
      }
#pragma unroll
      for (int r = 0; r < 4; ++r) {
        const float mnew = fmaxf(mxr[m][r], pm[r]);
        const float resc = __expf((mxr[m][r] - mnew) * scale);
        mxr[m][r] = mnew;
        smr[m][r] *= resc;
#pragma unroll
        for (int n2 = 0; n2 < 4; ++n2) oacc[m][n2][r] *= resc;
      }
#pragma unroll
      for (int n = 0; n < 4; ++n)
#pragma unroll
        for (int r = 0; r < 4; ++r) {
          const float e = __expf((sacc[m][n][r] - mxr[m][r]) * scale);
          smr[m][r] += e;
          const int row = m * 16 + q4 * 4 + r;
          const int byte = (row * 144 + (n * 16 + l15) * 2) ^ (((row >> 3) & 1) << 5);
          *(short*)(spw + byte) = f2bf(e);
        }
    }

    // ---- O += P V ----
#pragma unroll
    for (int ks = 0; ks < 2; ++ks) {
      short8 pf[MB];
#pragma unroll
      for (int m = 0; m < MB; ++m) {
        const int row = m * 16 + l15;
        const int byte = (row * 144 + ks * 64 + q4 * 16) ^ (((row >> 3) & 1) << 5);
        pf[m] = *(const short8*)(spw + byte);
      }
#pragma unroll
      for (int n2 = 0; n2 < 4; ++n2) {
        const int db = n2 * 16 + l15;
        short8 vf = *(const short8*)(vt + ((db * 144 + (ks * 32 + q4 * 8) * 2) ^
                                           (((db >> 3) & 7) << 4)));
#pragma unroll
        for (int m = 0; m < MB; ++m)
          oacc[m][n2] = mfma16(pf[m], vf, oacc[m][n2]);
      }
    }
  }

  // ---- epilogue: reduce row-sums, normalize, store ----
  short* ob = outb + (long)wv * QW * 768;
#pragma unroll
  for (int m = 0; m < MB; ++m)
#pragma unroll
    for (int r = 0; r < 4; ++r) {
      float s = smr[m][r];
      s += __shfl_xor(s, 1);
      s += __shfl_xor(s, 2);
      s += __shfl_xor(s, 4);
      s += __shfl_xor(s, 8);
      const float inv = 1.f / s;
#pragma unroll
      for (int n2 = 0; n2 < 4; ++n2)
        ob[(m * 16 + q4 * 4 + r) * 768 + n2 * 16 + l15] = f2bf(oacc[m][n2][r] * inv);
    }
}

// ------- Proj GEMM: out[r][j] = sum_k Xa[r][k]*Pw[j][k] + pb[j] (fp32 out) -----
__global__ __launch_bounds__(512, 2) void gemm_proj_k(
    const short* __restrict__ mt, const short* __restrict__ sA,
    const short* __restrict__ sh,
    const short* __restrict__ W, const float* __restrict__ bias,
    float* __restrict__ out, int cb0) {
  extern __shared__ char lds[];
  const int tid = threadIdx.x, lane = tid & 63, wv = tid >> 6;
  const int l15 = lane & 15, q4 = lane >> 4;
  const int m0 = blockIdx.x * 256, n0 = blockIdx.y * 256;
  const short* s = blockIdx.z ? sh : sA;

  int srow[2], coff[2];
  stage_geom(wv, lane, srow, coff);
  auto arow = [&](int r) -> const short* {
    const int ba = r / 384, na = r % 384;
    return na < 128 ? (mt + ((long)ba * 128 + na) * 768)
                    : (s + ((long)ba * 256 + (na - 128)) * 768);
  };
  const short* a00 = arow(m0 + srow[0]) + coff[0];
  const short* a01 = arow(m0 + srow[1]) + coff[1];
  const short* a10 = arow(m0 + 128 + srow[0]) + coff[0];
  const short* a11 = arow(m0 + 128 + srow[1]) + coff[1];
  const short* b00 = W + (long)(n0 + srow[0]) * 768 + coff[0];
  const short* b01 = W + (long)(n0 + srow[1]) * 768 + coff[1];
  const short* b10 = W + (long)(n0 + 128 + srow[0]) * 768 + coff[0];
  const short* b11 = W + (long)(n0 + 128 + srow[1]) * 768 + coff[1];

  f32x4 acc[8][4] = {};
  gemm256_core(a00, a01, a10, a11, b00, b01, b10, b11, lds, wv, lane, acc);

  const int wm = wv & 1, wn = wv >> 1;
#pragma unroll
  for (int n = 0; n < 4; ++n) {
    const int col = n0 + wn * 64 + n * 16 + l15;
    const float bvv = bias[col];
#pragma unroll
    for (int m = 0; m < 8; ++m)
#pragma unroll
      for (int r = 0; r < 4; ++r) {
        const int row = m0 + wm * 128 + m * 16 + q4 * 4 + r;
        out[(long)blockIdx.z * 18874368 + ((long)cb0 * 384 + row) * 768 + col] =
            acc[m][n][r] + bvv;
      }
  }
}

extern "C" void kernel_launch(void* const* d_in, const int* in_sizes, int n_in,
                              void* d_out, int out_size, void* d_ws, size_t ws_size,
                              hipStream_t stream) {
  (void)in_sizes; (void)n_in; (void)out_size;
  const float* x  = (const float*)d_in[0];
  const float* xh = (const float*)d_in[1];
  const float* qw = (const float*)d_in[2];
  const float* pw = (const float*)d_in[3];
  const float* pb = (const float*)d_in[4];
  float* out = (float*)d_out;

  const long qwSz = 2304L * 768 * 2;
  const long pwSz = 768L * 768 * 2;
  const long fixedW = qwSz + pwSz;
  const long perBatch = (2L * 384 * 768 + 2L * 384 * 2304 + 640L * 768) * 2;
  int CB = 64;
  while (CB > 2 && (long)CB * perBatch + fixedW > (long)ws_size) CB >>= 1;

  char* ws = (char*)d_ws;
  short* qwbf = (short*)ws;
  short* pwbf = (short*)(ws + qwSz);
  char* dyn = ws + fixedW;
  const long xbfSz = (long)CB * 384 * 768 * 2;
  const long qkvSz = (long)CB * 384 * 2304 * 2;
  const long mtSz  = (long)CB * 128 * 768 * 2;
  const long sSz   = (long)CB * 256 * 768 * 2;
  short* xbf  = (short*)dyn;
  short* xhbf = (short*)(dyn + xbfSz);
  short* qkvx = (short*)(dyn + 2 * xbfSz);
  short* qkvh = (short*)(dyn + 2 * xbfSz + qkvSz);
  short* amt  = (short*)(dyn + 2 * xbfSz + 2 * qkvSz);
  short* as_  = (short*)(dyn + 2 * xbfSz + 2 * qkvSz + mtSz);
  short* ash  = (short*)(dyn + 2 * xbfSz + 2 * qkvSz + mtSz + sSz);

  cvt_k<<<864, 256, 0, stream>>>(qw, qwbf, 2304L * 768 / 8);
  cvt_k<<<288, 256, 0, stream>>>(pw, pwbf, 768L * 768 / 8);

  const int nch = 64 / CB;
  for (int c = 0; c < nch; ++c) {
    const int cb0 = c * CB;
    const long n8 = (long)CB * 384 * 768 / 8;
    cvt_k<<<2048, 256, 0, stream>>>(x + (long)cb0 * 384 * 768, xbf, n8);
    cvt_k<<<2048, 256, 0, stream>>>(xh + (long)cb0 * 384 * 768, xhbf, n8);
    dim3 g1((CB * 384) / 256, 9, 2);
    gemm_qkv_k<<<g1, 512, 131072, stream>>>(xbf, xhbf, qwbf, qkvx, qkvh);
    attn_f<128, 16><<<dim3(CB, 12, 1), 512, 0, stream>>>(qkvx, qkvh, amt, as_, ash);
    attn_f<384, 32><<<dim3(CB, 12, 2), 512, 0, stream>>>(qkvx, qkvh, amt, as_, ash);
    dim3 g3((CB * 384) / 256, 3, 2);
    gemm_proj_k<<<g3, 512, 131072, stream>>>(amt, as_, ash, pwbf, pb, out, cb0);
  }
}